// Round 1
// baseline (717.654 us; speedup 1.0000x reference)
//
#include <hip/hip_runtime.h>

#define B_SZ   4096
#define IN_SZ  1024
#define V_SZ   48
#define H_SZ   512
#define OUT_SZ 64

typedef __attribute__((ext_vector_type(4))) float f32x4;
typedef __attribute__((ext_vector_type(8))) short bf16x8;   // 8 bf16 in 4 VGPRs
typedef __attribute__((ext_vector_type(4))) short short4v;
typedef __attribute__((ext_vector_type(4))) float float4v;

// fp32 -> bf16 round-to-nearest-even
__device__ __forceinline__ short f2bf(float f){
    unsigned u = __builtin_bit_cast(unsigned, f);
    u += 0x7fffu + ((u >> 16) & 1u);
    return (short)(u >> 16);
}

// async global->LDS, 16B per lane; LDS dest must be wave-uniform base + lane*16
__device__ __forceinline__ void gl2lds16(const void* g, void* l){
    __builtin_amdgcn_global_load_lds(
        (const __attribute__((address_space(1))) void*)g,
        (__attribute__((address_space(3))) void*)l, 16, 0, 0);
}

// ---------------- pre-pass: convert x to bf16 ----------------
__global__ void k_convert_x(const float* __restrict__ x, short* __restrict__ xb){
    int i = blockIdx.x * 256 + threadIdx.x;          // one float4 per thread
    float4v f = ((const float4v*)x)[i];
    short4v o = { f2bf(f.x), f2bf(f.y), f2bf(f.z), f2bf(f.w) };
    ((short4v*)xb)[i] = o;
}

// ---------------- pre-pass: out[v][c][r] = bf16(in[v][r][c]) ----------------
// 64x64 tiles through LDS; block (64,4)
__global__ void k_transpose_cvt(const float* __restrict__ in, short* __restrict__ out,
                                int R, int C){
    __shared__ short t[64][66];
    int v  = blockIdx.z;
    int c0 = blockIdx.x * 64, r0 = blockIdx.y * 64;
    int tx = threadIdx.x, ty = threadIdx.y;
    size_t base = (size_t)v * R * C;
    const float* inp = in + base + (size_t)r0 * C + c0;
    #pragma unroll
    for (int j = 0; j < 16; ++j){
        int r = ty + j*4;
        t[r][tx] = f2bf(inp[(size_t)r * C + tx]);
    }
    __syncthreads();
    short* outp = out + base + (size_t)c0 * R + r0;
    #pragma unroll
    for (int j = 0; j < 16; ++j){
        int cc = ty + j*4;
        outp[(size_t)cc * R + tx] = t[tx][cc];
    }
}

// ---------------- layer 1: h1[v][b][h] = relu(x @ W1[v] + b1[v]) ----------------
// m97 structure: 256 thr (2x2 waves, 64x64/wave), BM=BN=128, BK=64.
// LDS tiles stored as 16B units, unit-swizzled (w ^ (row&7)) via global-address
// permutation so frag ds_read_b128 is 2-way max (free).
__global__ __launch_bounds__(256) void k_gemm1(
    const short* __restrict__ xb, const short* __restrict__ W1t,
    const float* __restrict__ b1, short* __restrict__ h1)
{
    __shared__ __align__(16) short As[128*64];
    __shared__ __align__(16) short Bs[128*64];
    const int tid  = threadIdx.x;
    const int lane = tid & 63, wave = tid >> 6;
    const int l15  = lane & 15, quad = lane >> 4;
    const int wm = wave & 1, wn = wave >> 1;
    const int M0 = blockIdx.x * 128;
    const int N0 = blockIdx.y * 128;
    const int v  = blockIdx.z;

    const short* a_base = xb  + (size_t)M0 * IN_SZ;
    const short* b_base = W1t + ((size_t)v * H_SZ + N0) * IN_SZ;

    // precompute staging source pointers (k0-invariant) and LDS bases
    const short* asrc[4]; const short* bsrc[4]; short* adst[4]; short* bdst[4];
    #pragma unroll
    for (int j = 0; j < 4; ++j){
        int p   = j*256 + tid;
        int row = p >> 3;
        int w   = (p & 7) ^ (row & 7);
        asrc[j] = a_base + (size_t)row * IN_SZ + w*8;
        bsrc[j] = b_base + (size_t)row * IN_SZ + w*8;
        adst[j] = &As[(size_t)(j*256 + (tid & ~63)) * 8];
        bdst[j] = &Bs[(size_t)(j*256 + (tid & ~63)) * 8];
    }

    f32x4 acc[4][4];
    #pragma unroll
    for (int i = 0; i < 4; ++i)
        #pragma unroll
        for (int j = 0; j < 4; ++j) acc[i][j] = (f32x4){0.f,0.f,0.f,0.f};

    for (int k0 = 0; k0 < IN_SZ; k0 += 64){
        #pragma unroll
        for (int j = 0; j < 4; ++j){
            gl2lds16(asrc[j] + k0, adst[j]);
            gl2lds16(bsrc[j] + k0, bdst[j]);
        }
        __syncthreads();
        #pragma unroll
        for (int kk = 0; kk < 2; ++kk){
            bf16x8 a[4], b[4];
            #pragma unroll
            for (int tm = 0; tm < 4; ++tm){
                int m = wm*64 + tm*16 + l15;
                int slot = m*8 + ((kk*4 + quad) ^ (m & 7));
                a[tm] = *(const bf16x8*)&As[slot*8];
            }
            #pragma unroll
            for (int tn = 0; tn < 4; ++tn){
                int n = wn*64 + tn*16 + l15;
                int slot = n*8 + ((kk*4 + quad) ^ (n & 7));
                b[tn] = *(const bf16x8*)&Bs[slot*8];
            }
            #pragma unroll
            for (int tm = 0; tm < 4; ++tm)
                #pragma unroll
                for (int tn = 0; tn < 4; ++tn)
                    acc[tm][tn] = __builtin_amdgcn_mfma_f32_16x16x32_bf16(
                        a[tm], b[tn], acc[tm][tn], 0, 0, 0);
        }
        __syncthreads();
    }

    // epilogue: bias + relu + bf16 -> h1[v][row][col]
    const float* b1v = b1 + v * H_SZ;
    short* h1v = h1 + (size_t)v * B_SZ * H_SZ;
    #pragma unroll
    for (int tn = 0; tn < 4; ++tn){
        int col = N0 + wn*64 + tn*16 + l15;
        float bias = b1v[col];
        #pragma unroll
        for (int tm = 0; tm < 4; ++tm){
            int rowb = M0 + wm*64 + tm*16 + quad*4;
            #pragma unroll
            for (int r = 0; r < 4; ++r){
                float val = acc[tm][tn][r] + bias;
                val = val > 0.f ? val : 0.f;
                h1v[(size_t)(rowb + r) * H_SZ + col] = f2bf(val);
            }
        }
    }
}

// ---------------- layers 2+3 fused ----------------
// 512 thr (8 waves). Phase 2: BM=128, BN=256 x 2 passes, BK=32, wave 64x64;
// h2 -> 128KB swizzled LDS. Phase 3: K=512 from LDS, W3t B-frags direct global.
__global__ __launch_bounds__(512) void k_gemm23(
    const short* __restrict__ h1, const short* __restrict__ W2t,
    const float* __restrict__ b2, const short* __restrict__ W3t,
    float* __restrict__ out)
{
    __shared__ __align__(16) short h2s[128*512];   // 128KB
    __shared__ __align__(16) short As[128*32];     // 8KB
    __shared__ __align__(16) short Bs[256*32];     // 16KB
    const int tid  = threadIdx.x;
    const int lane = tid & 63, wave = tid >> 6;
    const int l15  = lane & 15, quad = lane >> 4;
    const int M0 = blockIdx.x * 128;
    const int v  = blockIdx.y;
    const short* h1v = h1  + (size_t)v * B_SZ * H_SZ + (size_t)M0 * H_SZ;
    const short* w2v = W2t + (size_t)v * H_SZ * H_SZ;
    const float* b2v = b2  + v * H_SZ;
    const short* w3v = W3t + (size_t)v * OUT_SZ * H_SZ;

    const int wm = wave & 1, wn = wave >> 1;   // phase2: 2m x 4n

    // staging descriptors (BK=32 wrap-swizzle: 2 rows per 128B wrap)
    int pA = tid;
    int wrapA = pA >> 3, posA = (pA & 7) ^ (wrapA & 7);
    int rowA = wrapA*2 + (posA >> 2), wA = posA & 3;
    const short* asrc = h1v + (size_t)rowA * H_SZ + wA*8;
    short* adst = &As[(size_t)(tid & ~63) * 8];
    const short* bsrc[2]; short* bdst[2]; int browg[2];
    #pragma unroll
    for (int j = 0; j < 2; ++j){
        int p = j*512 + tid;
        int wrapI = p >> 3, posL = (p & 7) ^ (wrapI & 7);
        int row = wrapI*2 + (posL >> 2), w = posL & 3;
        browg[j] = row;
        bsrc[j] = w2v + (size_t)row * H_SZ + w*8;
        bdst[j] = &Bs[(size_t)(j*512 + (tid & ~63)) * 8];
    }

    for (int np = 0; np < 2; ++np){
        const int N0 = np * 256;
        f32x4 acc[4][4];
        #pragma unroll
        for (int i = 0; i < 4; ++i)
            #pragma unroll
            for (int j = 0; j < 4; ++j) acc[i][j] = (f32x4){0.f,0.f,0.f,0.f};

        for (int k0 = 0; k0 < H_SZ; k0 += 32){
            gl2lds16(asrc + k0, adst);
            #pragma unroll
            for (int j = 0; j < 2; ++j)
                gl2lds16(bsrc[j] + (size_t)N0 * H_SZ + k0, bdst[j]);
            __syncthreads();
            bf16x8 a[4], b[4];
            #pragma unroll
            for (int tm = 0; tm < 4; ++tm){
                int m = wm*64 + tm*16 + l15;
                int slot = (m>>1)*8 + ((((m&1)<<2) | quad) ^ ((m>>1) & 7));
                a[tm] = *(const bf16x8*)&As[slot*8];
            }
            #pragma unroll
            for (int tn = 0; tn < 4; ++tn){
                int n = wn*64 + tn*16 + l15;
                int slot = (n>>1)*8 + ((((n&1)<<2) | quad) ^ ((n>>1) & 7));
                b[tn] = *(const bf16x8*)&Bs[slot*8];
            }
            #pragma unroll
            for (int tm = 0; tm < 4; ++tm)
                #pragma unroll
                for (int tn = 0; tn < 4; ++tn)
                    acc[tm][tn] = __builtin_amdgcn_mfma_f32_16x16x32_bf16(
                        a[tm], b[tn], acc[tm][tn], 0, 0, 0);
            __syncthreads();
        }
        // epilogue -> h2s (unit-swizzled [128][512])
        #pragma unroll
        for (int tn = 0; tn < 4; ++tn){
            int n = N0 + wn*64 + tn*16 + l15;
            float bias = b2v[n];
            int u = n >> 3;
            #pragma unroll
            for (int tm = 0; tm < 4; ++tm){
                int rowb = wm*64 + tm*16 + quad*4;
                #pragma unroll
                for (int r = 0; r < 4; ++r){
                    int row = rowb + r;
                    float val = acc[tm][tn][r] + bias;
                    val = val > 0.f ? val : 0.f;
                    int slot = row*64 + (u ^ (row & 7));
                    h2s[slot*8 + (n & 7)] = f2bf(val);
                }
            }
        }
    }
    __syncthreads();

    // phase 3: o = h2 @ W3[v];  8 waves = 2m x 4n(16-wide)
    const int wn3 = wave & 3, wm3 = wave >> 2;
    f32x4 acc3[4];
    #pragma unroll
    for (int i = 0; i < 4; ++i) acc3[i] = (f32x4){0.f,0.f,0.f,0.f};
    const int n3 = wn3*16 + l15;
    for (int kk = 0; kk < 16; ++kk){
        int kbase = kk*32 + quad*8;
        bf16x8 bfrag = *(const bf16x8*)&w3v[(size_t)n3 * H_SZ + kbase];
        int u = kbase >> 3;
        #pragma unroll
        for (int tm = 0; tm < 4; ++tm){
            int m = wm3*64 + tm*16 + l15;
            int slot = m*64 + (u ^ (m & 7));
            bf16x8 afrag = *(const bf16x8*)&h2s[slot*8];
            acc3[tm] = __builtin_amdgcn_mfma_f32_16x16x32_bf16(afrag, bfrag, acc3[tm], 0, 0, 0);
        }
    }
    #pragma unroll
    for (int tm = 0; tm < 4; ++tm){
        int rowb = M0 + wm3*64 + tm*16 + quad*4;
        int col  = v*OUT_SZ + wn3*16 + l15;
        #pragma unroll
        for (int r = 0; r < 4; ++r)
            out[(size_t)(rowb + r) * (V_SZ*OUT_SZ) + col] = acc3[tm][r];
    }
}

extern "C" void kernel_launch(void* const* d_in, const int* in_sizes, int n_in,
                              void* d_out, int out_size, void* d_ws, size_t ws_size,
                              hipStream_t stream)
{
    (void)in_sizes; (void)n_in; (void)out_size; (void)ws_size;
    const float* x  = (const float*)d_in[0];
    const float* W1 = (const float*)d_in[1];
    const float* b1 = (const float*)d_in[2];
    const float* W2 = (const float*)d_in[3];
    const float* b2 = (const float*)d_in[4];
    const float* W3 = (const float*)d_in[5];
    float* out = (float*)d_out;

    // workspace layout (bf16 shorts), total ~275 MB
    char* ws = (char*)d_ws;
    short* xb  = (short*)ws;  ws += (size_t)B_SZ * IN_SZ * 2;
    short* W1t = (short*)ws;  ws += (size_t)V_SZ * H_SZ * IN_SZ * 2;      // [v][h][i]
    short* W2t = (short*)ws;  ws += (size_t)V_SZ * H_SZ * H_SZ * 2;       // [v][n][k]
    short* W3t = (short*)ws;  ws += (size_t)V_SZ * OUT_SZ * H_SZ * 2;     // [v][o][k]
    short* h1  = (short*)ws;                                              // [v][b][h]

    k_convert_x<<<dim3(B_SZ*IN_SZ/1024), dim3(256), 0, stream>>>(x, xb);
    k_transpose_cvt<<<dim3(H_SZ/64,  IN_SZ/64, V_SZ), dim3(64,4), 0, stream>>>(W1, W1t, IN_SZ, H_SZ);
    k_transpose_cvt<<<dim3(H_SZ/64,  H_SZ/64,  V_SZ), dim3(64,4), 0, stream>>>(W2, W2t, H_SZ, H_SZ);
    k_transpose_cvt<<<dim3(OUT_SZ/64,H_SZ/64,  V_SZ), dim3(64,4), 0, stream>>>(W3, W3t, H_SZ, OUT_SZ);
    k_gemm1 <<<dim3(B_SZ/128, H_SZ/128, V_SZ), dim3(256), 0, stream>>>(xb, W1t, b1, h1);
    k_gemm23<<<dim3(B_SZ/128, V_SZ),           dim3(512), 0, stream>>>(h1, W2t, b2, W3t, out);
}